// Round 1
// baseline (69.559 us; speedup 1.0000x reference)
//
#include <hip/hip_runtime.h>

#define EPS 1e-5f

__device__ __forceinline__ float frelu(float x) { return x > 0.f ? x : 0.f; }
__device__ __forceinline__ float fast_rcp(float x) { return __builtin_amdgcn_rcpf(x); }
__device__ __forceinline__ float fast_rsq(float x) { return __builtin_amdgcn_rsqf(x); }

// One thread processes ROWS=4 consecutive rows so that paper/author (5 f32/row)
// and out (6 f32/row) are loadable/storable as aligned float4:
//   history: 4*2 = 8  f32 = 2 x float4   (offset 32B * tid, 16-aligned)
//   paper  : 4*5 = 20 f32 = 5 x float4   (offset 80B * tid, 16-aligned)
//   author : 4*5 = 20 f32 = 5 x float4
//   out    : 4*6 = 24 f32 = 6 x float4   (offset 96B * tid, 16-aligned)
__global__ __launch_bounds__(256) void shattn_kernel(
    const float* __restrict__ history,
    const float* __restrict__ paper,
    const float* __restrict__ author,
    const float* __restrict__ g_W_h, const float* __restrict__ g_b_h,
    const float* __restrict__ g_W_p, const float* __restrict__ g_b_p,
    const float* __restrict__ g_W_a, const float* __restrict__ g_b_a,
    const float* __restrict__ g_ln_w, const float* __restrict__ g_ln_b,
    const float* __restrict__ g_W_fc, const float* __restrict__ g_b_fc,
    float* __restrict__ out, int nrows)
{
    // ---- stage the 84 uniform parameters in LDS (broadcast reads are free) ----
    __shared__ float sp[84];
    {
        int t = threadIdx.x;
        if (t < 84) {
            float v;
            if      (t < 4)  v = g_W_h[t];
            else if (t < 6)  v = g_b_h[t - 4];
            else if (t < 16) v = g_W_p[t - 6];
            else if (t < 18) v = g_b_p[t - 16];
            else if (t < 28) v = g_W_a[t - 18];
            else if (t < 30) v = g_b_a[t - 28];
            else if (t < 36) v = g_ln_w[t - 30];
            else if (t < 42) v = g_ln_b[t - 36];
            else if (t < 78) v = g_W_fc[t - 42];
            else             v = g_b_fc[t - 78];
            sp[t] = v;
        }
    }
    __syncthreads();

    const float* W_h  = sp + 0;   // [2][2] row-major (torch: out = W @ x + b)
    const float* b_h  = sp + 4;
    const float* W_p  = sp + 6;   // [2][5]
    const float* b_p  = sp + 16;
    const float* W_a  = sp + 18;  // [2][5]
    const float* b_a  = sp + 28;
    const float* ln_w = sp + 30;  // [3][2]
    const float* ln_b = sp + 36;  // [3][2]
    const float* W_fc = sp + 42;  // [6][6]
    const float* b_fc = sp + 78;

    const size_t tid = (size_t)blockIdx.x * blockDim.x + threadIdx.x;
    const size_t r0  = tid * 4;
    if (r0 >= (size_t)nrows) return;

    float hbuf[8], pbuf[20], abuf[20], obuf[24];
    const bool full = (r0 + 4 <= (size_t)nrows);

    if (full) {
        const float4* h4 = reinterpret_cast<const float4*>(history + r0 * 2);
        const float4* p4 = reinterpret_cast<const float4*>(paper   + r0 * 5);
        const float4* a4 = reinterpret_cast<const float4*>(author  + r0 * 5);
        #pragma unroll
        for (int i = 0; i < 2; ++i) *reinterpret_cast<float4*>(&hbuf[4*i]) = h4[i];
        #pragma unroll
        for (int i = 0; i < 5; ++i) *reinterpret_cast<float4*>(&pbuf[4*i]) = p4[i];
        #pragma unroll
        for (int i = 0; i < 5; ++i) *reinterpret_cast<float4*>(&abuf[4*i]) = a4[i];
    } else {
        // tail: scalar loads for valid rows, zero-fill the rest (computed but not stored)
        #pragma unroll
        for (int i = 0; i < 8;  ++i) hbuf[i] = 0.f;
        #pragma unroll
        for (int i = 0; i < 20; ++i) { pbuf[i] = 0.f; abuf[i] = 0.f; }
        for (int r = 0; r < 4; ++r) {
            if (r0 + r < (size_t)nrows) {
                hbuf[2*r]   = history[(r0 + r)*2];
                hbuf[2*r+1] = history[(r0 + r)*2 + 1];
                for (int j = 0; j < 5; ++j) {
                    pbuf[5*r + j] = paper [(r0 + r)*5 + j];
                    abuf[5*r + j] = author[(r0 + r)*5 + j];
                }
            }
        }
    }

    #pragma unroll
    for (int r = 0; r < 4; ++r) {
        // --- three tiny Linear+ReLU projectors -> feat [3][2] ---
        float f[3][2];
        {
            float hx = hbuf[2*r], hy = hbuf[2*r+1];
            f[0][0] = frelu(W_h[0]*hx + W_h[1]*hy + b_h[0]);
            f[0][1] = frelu(W_h[2]*hx + W_h[3]*hy + b_h[1]);
        }
        {
            float s0 = b_p[0], s1 = b_p[1];
            #pragma unroll
            for (int j = 0; j < 5; ++j) {
                float x = pbuf[5*r + j];
                s0 += W_p[j]     * x;
                s1 += W_p[5 + j] * x;
            }
            f[1][0] = frelu(s0); f[1][1] = frelu(s1);
        }
        {
            float s0 = b_a[0], s1 = b_a[1];
            #pragma unroll
            for (int j = 0; j < 5; ++j) {
                float x = abuf[5*r + j];
                s0 += W_a[j]     * x;
                s1 += W_a[5 + j] * x;
            }
            f[2][0] = frelu(s0); f[2][1] = frelu(s1);
        }

        // --- logits[s][t] = <f_s, f_t>/sqrt(2); softmax over s (axis=1, per ref) ---
        const float inv_sqrt2 = 0.70710678118654752440f;
        float l[3][3];
        #pragma unroll
        for (int s = 0; s < 3; ++s)
            #pragma unroll
            for (int u = 0; u < 3; ++u)
                l[s][u] = (f[s][0]*f[u][0] + f[s][1]*f[u][1]) * inv_sqrt2;

        float w[3][3];
        #pragma unroll
        for (int u = 0; u < 3; ++u) {
            float m  = fmaxf(fmaxf(l[0][u], l[1][u]), l[2][u]);
            float e0 = __expf(l[0][u] - m);
            float e1 = __expf(l[1][u] - m);
            float e2 = __expf(l[2][u] - m);
            float inv = fast_rcp(e0 + e1 + e2);
            w[0][u] = e0 * inv; w[1][u] = e1 * inv; w[2][u] = e2 * inv;
        }

        // --- attended[s][d] = sum_t w[s][t] * f[t][d] ---
        float att[3][2];
        #pragma unroll
        for (int s = 0; s < 3; ++s) {
            att[s][0] = w[s][0]*f[0][0] + w[s][1]*f[1][0] + w[s][2]*f[2][0];
            att[s][1] = w[s][0]*f[0][1] + w[s][1]*f[1][1] + w[s][2]*f[2][1];
        }

        // --- LayerNorm over all 6 elements ---
        float mu = (att[0][0]+att[0][1]+att[1][0]+att[1][1]+att[2][0]+att[2][1]) * (1.f/6.f);
        float var = 0.f;
        #pragma unroll
        for (int s = 0; s < 3; ++s) {
            float d0 = att[s][0] - mu, d1 = att[s][1] - mu;
            var += d0*d0 + d1*d1;
        }
        var *= (1.f/6.f);
        float inv_std = fast_rsq(var + EPS);

        float flat[6];
        #pragma unroll
        for (int s = 0; s < 3; ++s) {
            flat[2*s]   = (att[s][0] - mu) * inv_std * ln_w[2*s]   + ln_b[2*s];
            flat[2*s+1] = (att[s][1] - mu) * inv_std * ln_w[2*s+1] + ln_b[2*s+1];
        }

        // --- final FC [6x6] + ReLU ---
        #pragma unroll
        for (int o = 0; o < 6; ++o) {
            float acc = b_fc[o];
            #pragma unroll
            for (int j = 0; j < 6; ++j) acc += flat[j] * W_fc[6*o + j];
            obuf[6*r + o] = frelu(acc);
        }
    }

    if (full) {
        float4* o4 = reinterpret_cast<float4*>(out + r0 * 6);
        #pragma unroll
        for (int i = 0; i < 6; ++i) o4[i] = *reinterpret_cast<float4*>(&obuf[4*i]);
    } else {
        for (int r = 0; r < 4; ++r)
            if (r0 + r < (size_t)nrows)
                for (int o = 0; o < 6; ++o)
                    out[(r0 + r)*6 + o] = obuf[6*r + o];
    }
}

extern "C" void kernel_launch(void* const* d_in, const int* in_sizes, int n_in,
                              void* d_out, int out_size, void* d_ws, size_t ws_size,
                              hipStream_t stream) {
    const float* history = (const float*)d_in[0];
    const float* paper   = (const float*)d_in[1];
    const float* author  = (const float*)d_in[2];
    const float* W_h  = (const float*)d_in[3];
    const float* b_h  = (const float*)d_in[4];
    const float* W_p  = (const float*)d_in[5];
    const float* b_p  = (const float*)d_in[6];
    const float* W_a  = (const float*)d_in[7];
    const float* b_a  = (const float*)d_in[8];
    const float* ln_w = (const float*)d_in[9];
    const float* ln_b = (const float*)d_in[10];
    const float* W_fc = (const float*)d_in[11];
    const float* b_fc = (const float*)d_in[12];
    float* out = (float*)d_out;

    const int nrows = in_sizes[0] / 2;          // history is [B,2]
    const int nthreads = (nrows + 3) / 4;       // 4 rows per thread
    const int block = 256;
    const int grid = (nthreads + block - 1) / block;

    shattn_kernel<<<grid, block, 0, stream>>>(
        history, paper, author,
        W_h, b_h, W_p, b_p, W_a, b_a, ln_w, ln_b, W_fc, b_fc,
        out, nrows);
}

// Round 2
// 59.769 us; speedup vs baseline: 1.1638x; 1.1638x over previous
//
#include <hip/hip_runtime.h>

#define EPS 1e-5f

__device__ __forceinline__ float frelu(float x) { return x > 0.f ? x : 0.f; }
__device__ __forceinline__ float fast_rcp(float x) { return __builtin_amdgcn_rcpf(x); }
__device__ __forceinline__ float fast_rsq(float x) { return __builtin_amdgcn_rsqf(x); }

// Block = 512 threads, 1 row per thread (B = 4194304 = 8192 * 512, no tail).
// paper/author (5 f32/row, 20 B -- not per-row vectorizable) are staged
// through LDS with fully-coalesced float4 global loads; per-thread LDS reads
// lds[5t+j] hit bank (5t+j)%32, gcd(5,32)=1 -> 2 lanes/bank = conflict-free.
// history (8 B/row) and out (24 B/row) go direct (float2 lanes, contiguous).
__global__ __launch_bounds__(512) void shattn_kernel(
    const float* __restrict__ history,
    const float* __restrict__ paper,
    const float* __restrict__ author,
    const float* __restrict__ g_W_h, const float* __restrict__ g_b_h,
    const float* __restrict__ g_W_p, const float* __restrict__ g_b_p,
    const float* __restrict__ g_W_a, const float* __restrict__ g_b_a,
    const float* __restrict__ g_ln_w, const float* __restrict__ g_ln_b,
    const float* __restrict__ g_W_fc, const float* __restrict__ g_b_fc,
    float* __restrict__ out, int nrows)
{
    __shared__ float sp[84];        // uniform parameters
    __shared__ float pap[2560];     // 512 rows x 5 f32 = 10 KB
    __shared__ float aut[2560];     // 10 KB

    const int t = threadIdx.x;
    const int gtid = blockIdx.x * 512 + t;

    // ---- issue history load early (coalesced float2/lane) ----
    float2 hrow = make_float2(0.f, 0.f);
    if (gtid < nrows)
        hrow = reinterpret_cast<const float2*>(history)[gtid];

    // ---- stage parameters ----
    if (t < 84) {
        float v;
        if      (t < 4)  v = g_W_h[t];
        else if (t < 6)  v = g_b_h[t - 4];
        else if (t < 16) v = g_W_p[t - 6];
        else if (t < 18) v = g_b_p[t - 16];
        else if (t < 28) v = g_W_a[t - 18];
        else if (t < 30) v = g_b_a[t - 28];
        else if (t < 36) v = g_ln_w[t - 30];
        else if (t < 42) v = g_ln_b[t - 36];
        else if (t < 78) v = g_W_fc[t - 42];
        else             v = g_b_fc[t - 78];
        sp[t] = v;
    }

    // ---- coalesced stage of paper/author tiles: 640 float4 each ----
    {
        const size_t rowbase = (size_t)blockIdx.x * 512;
        const float4* p4 = reinterpret_cast<const float4*>(paper  + rowbase * 5);
        const float4* a4 = reinterpret_cast<const float4*>(author + rowbase * 5);
        float4* pl = reinterpret_cast<float4*>(pap);
        float4* al = reinterpret_cast<float4*>(aut);
        // i = 0: all 512 threads; i = 1: first 128 threads (640 total)
        pl[t] = p4[t];
        al[t] = a4[t];
        if (t < 128) {
            pl[512 + t] = p4[512 + t];
            al[512 + t] = a4[512 + t];
        }
    }
    __syncthreads();

    if (gtid >= nrows) return;

    const float* W_h  = sp + 0;
    const float* b_h  = sp + 4;
    const float* W_p  = sp + 6;
    const float* b_p  = sp + 16;
    const float* W_a  = sp + 18;
    const float* b_a  = sp + 28;
    const float* ln_w = sp + 30;
    const float* ln_b = sp + 36;
    const float* W_fc = sp + 42;
    const float* b_fc = sp + 78;

    // ---- per-row compute ----
    float f[3][2];
    {
        f[0][0] = frelu(W_h[0]*hrow.x + W_h[1]*hrow.y + b_h[0]);
        f[0][1] = frelu(W_h[2]*hrow.x + W_h[3]*hrow.y + b_h[1]);
    }
    {
        float s0 = b_p[0], s1 = b_p[1];
        #pragma unroll
        for (int j = 0; j < 5; ++j) {
            float x = pap[5*t + j];
            s0 += W_p[j]     * x;
            s1 += W_p[5 + j] * x;
        }
        f[1][0] = frelu(s0); f[1][1] = frelu(s1);
    }
    {
        float s0 = b_a[0], s1 = b_a[1];
        #pragma unroll
        for (int j = 0; j < 5; ++j) {
            float x = aut[5*t + j];
            s0 += W_a[j]     * x;
            s1 += W_a[5 + j] * x;
        }
        f[2][0] = frelu(s0); f[2][1] = frelu(s1);
    }

    // logits[s][u] = <f_s,f_u>/sqrt(2); softmax over s (axis=1)
    const float inv_sqrt2 = 0.70710678118654752440f;
    float l[3][3];
    #pragma unroll
    for (int s = 0; s < 3; ++s)
        #pragma unroll
        for (int u = 0; u < 3; ++u)
            l[s][u] = (f[s][0]*f[u][0] + f[s][1]*f[u][1]) * inv_sqrt2;

    float w[3][3];
    #pragma unroll
    for (int u = 0; u < 3; ++u) {
        float m  = fmaxf(fmaxf(l[0][u], l[1][u]), l[2][u]);
        float e0 = __expf(l[0][u] - m);
        float e1 = __expf(l[1][u] - m);
        float e2 = __expf(l[2][u] - m);
        float inv = fast_rcp(e0 + e1 + e2);
        w[0][u] = e0 * inv; w[1][u] = e1 * inv; w[2][u] = e2 * inv;
    }

    float att[3][2];
    #pragma unroll
    for (int s = 0; s < 3; ++s) {
        att[s][0] = w[s][0]*f[0][0] + w[s][1]*f[1][0] + w[s][2]*f[2][0];
        att[s][1] = w[s][0]*f[0][1] + w[s][1]*f[1][1] + w[s][2]*f[2][1];
    }

    // LayerNorm over all 6 elements
    float mu = (att[0][0]+att[0][1]+att[1][0]+att[1][1]+att[2][0]+att[2][1]) * (1.f/6.f);
    float var = 0.f;
    #pragma unroll
    for (int s = 0; s < 3; ++s) {
        float d0 = att[s][0] - mu, d1 = att[s][1] - mu;
        var += d0*d0 + d1*d1;
    }
    var *= (1.f/6.f);
    float inv_std = fast_rsq(var + EPS);

    float flat[6];
    #pragma unroll
    for (int s = 0; s < 3; ++s) {
        flat[2*s]   = (att[s][0] - mu) * inv_std * ln_w[2*s]   + ln_b[2*s];
        flat[2*s+1] = (att[s][1] - mu) * inv_std * ln_w[2*s+1] + ln_b[2*s+1];
    }

    // final FC [6x6] + ReLU, stored as 3x float2 (24 B/row, 8-aligned)
    float obuf[6];
    #pragma unroll
    for (int o = 0; o < 6; ++o) {
        float acc = b_fc[o];
        #pragma unroll
        for (int j = 0; j < 6; ++j) acc += flat[j] * W_fc[6*o + j];
        obuf[o] = frelu(acc);
    }

    float2* o2 = reinterpret_cast<float2*>(out + (size_t)gtid * 6);
    o2[0] = make_float2(obuf[0], obuf[1]);
    o2[1] = make_float2(obuf[2], obuf[3]);
    o2[2] = make_float2(obuf[4], obuf[5]);
}

extern "C" void kernel_launch(void* const* d_in, const int* in_sizes, int n_in,
                              void* d_out, int out_size, void* d_ws, size_t ws_size,
                              hipStream_t stream) {
    const float* history = (const float*)d_in[0];
    const float* paper   = (const float*)d_in[1];
    const float* author  = (const float*)d_in[2];
    const float* W_h  = (const float*)d_in[3];
    const float* b_h  = (const float*)d_in[4];
    const float* W_p  = (const float*)d_in[5];
    const float* b_p  = (const float*)d_in[6];
    const float* W_a  = (const float*)d_in[7];
    const float* b_a  = (const float*)d_in[8];
    const float* ln_w = (const float*)d_in[9];
    const float* ln_b = (const float*)d_in[10];
    const float* W_fc = (const float*)d_in[11];
    const float* b_fc = (const float*)d_in[12];
    float* out = (float*)d_out;

    const int nrows = in_sizes[0] / 2;             // history is [B,2]
    const int block = 512;
    const int grid  = (nrows + block - 1) / block; // B = 8192*512 exactly

    shattn_kernel<<<grid, block, 0, stream>>>(
        history, paper, author,
        W_h, b_h, W_p, b_p, W_a, b_a, ln_w, ln_b, W_fc, b_fc,
        out, nrows);
}